// Round 10
// baseline (705.417 us; speedup 1.0000x reference)
//
#include <hip/hip_runtime.h>
#include <stdint.h>

// Problem constants: B=4, N=32768, K=16, nqueries=2048, stride=16.
#define NPTS  32768
#define NQ    2048
#define KNN   16
#define NB    4
#define BLOCK 256
#define HALF  16384           // points per half-stream (split-K = 2)
#define PPL   8               // points per lane per iteration (16 ILP chains)
#define ITERS (HALF / (64 * PPL))   // 32

__device__ __forceinline__ int dpp_shr1_i(int x) {
    // row_shr:1 within 16-lane rows; row-start lane keeps old (bound_ctrl=0)
    return __builtin_amdgcn_update_dpp(x, x, 0x111, 0xf, 0xf, false);
}
__device__ __forceinline__ float dpp_shr1_f(float x) {
    return __int_as_float(dpp_shr1_i(__float_as_int(x)));
}
__device__ __forceinline__ float readlane_f(float x, int l) {
    return __int_as_float(__builtin_amdgcn_readlane(__float_as_int(x), l));
}

// Exact distributed top-16 for query T (0/1): sorted list (ascending by
// (dist,idx)) in lanes 16T..16T+15; lane 16T+15 holds the exact threshold tau.
// d is the EXACT numpy distance. tg = tau*(1+1e-5) (margin ~40x the
// fma-vs-numpy rounding gap) refreshed once per call (gate uses tg; the
// in-loop re-gate uses exact tau).
template <int T>
__device__ __forceinline__ void insert_all(float d, int p, int lane,
                                           float& ld, int& li, float& tau, float& tg)
{
    unsigned long long rem = __ballot(d <= tau);
    while (rem) {
        const int srcl = __ffsll(rem) - 1;           // wave-uniform
        const float wd = readlane_f(d, srcl);
        const int   wi = __builtin_amdgcn_readlane(p, srcl);
        const bool less = (ld < wd) || (ld == wd && li < wi);
        const unsigned long long lm = __ballot(less);
        const int pos = __popc((unsigned)((lm >> (16 * T)) & 0xffffull));
        const float pld = dpp_shr1_f(ld);
        const int   pli = dpp_shr1_i(li);
        if ((lane >> 4) == T) {
            const int gl = lane & 15;
            if (gl == pos)      { ld = wd;  li = wi;  }
            else if (gl > pos)  { ld = pld; li = pli; }
        }
        tau = readlane_f(ld, 16 * T + 15);
        rem &= rem - 1;
        if (rem) rem &= __ballot(d <= tau);          // re-gate survivors (exact)
    }
    tg = tau * 1.00001f;
}

__device__ __forceinline__ void load6(float4 dst[6], const float4* p) {
    #pragma unroll
    for (int t = 0; t < 6; ++t) dst[t] = p[t];
}

// One 512-point step: 8 pts/lane, 16 independent FMA-gate chains, exact
// recompute + exact insert for accepted slots.
__device__ __forceinline__ void step(const float4 c[6], int pb, int lane,
                                     float qx0, float qy0, float qz0,
                                     float qx1, float qy1, float qz1,
                                     float& ld, int& li,
                                     float& tau0, float& tau1,
                                     float& tg0, float& tg1)
{
    float px[PPL], py[PPL], pz[PPL];                 // pure register renames
    px[0] = c[0].x; py[0] = c[0].y; pz[0] = c[0].z;
    px[1] = c[0].w; py[1] = c[1].x; pz[1] = c[1].y;
    px[2] = c[1].z; py[2] = c[1].w; pz[2] = c[2].x;
    px[3] = c[2].y; py[3] = c[2].z; pz[3] = c[2].w;
    px[4] = c[3].x; py[4] = c[3].y; pz[4] = c[3].z;
    px[5] = c[3].w; py[5] = c[4].x; pz[5] = c[4].y;
    px[6] = c[4].z; py[6] = c[4].w; pz[6] = c[5].x;
    px[7] = c[5].y; py[7] = c[5].z; pz[7] = c[5].w;

    unsigned long long m0[PPL], m1[PPL], any = 0;
    #pragma unroll
    for (int j = 0; j < PPL; ++j) {                  // 16 independent chains
        const float ax = px[j] - qx0, ay = py[j] - qy0, az = pz[j] - qz0;
        const float g0 = __fmaf_rn(az, az, __fmaf_rn(ay, ay, __fmul_rn(ax, ax)));
        m0[j] = __ballot(g0 <= tg0);
        const float bx = px[j] - qx1, by = py[j] - qy1, bz = pz[j] - qz1;
        const float g1 = __fmaf_rn(bz, bz, __fmaf_rn(by, by, __fmul_rn(bx, bx)));
        m1[j] = __ballot(g1 <= tg1);
        any |= m0[j] | m1[j];
    }
    if (any) {
        #pragma unroll
        for (int j = 0; j < PPL; ++j) {
            if (m0[j]) {                             // exact numpy distance
                const float dx = __fadd_rn(px[j], -qx0);
                const float dy = __fadd_rn(py[j], -qy0);
                const float dz = __fadd_rn(pz[j], -qz0);
                const float d  = __fadd_rn(
                    __fadd_rn(__fmul_rn(dx, dx), __fmul_rn(dy, dy)),
                    __fmul_rn(dz, dz));
                insert_all<0>(d, pb + j, lane, ld, li, tau0, tg0);
            }
        }
        #pragma unroll
        for (int j = 0; j < PPL; ++j) {
            if (m1[j]) {
                const float dx = __fadd_rn(px[j], -qx1);
                const float dy = __fadd_rn(py[j], -qy1);
                const float dz = __fadd_rn(pz[j], -qz1);
                const float d  = __fadd_rn(
                    __fadd_rn(__fmul_rn(dx, dx), __fmul_rn(dy, dy)),
                    __fmul_rn(dz, dz));
                insert_all<1>(d, pb + j, lane, ld, li, tau1, tg1);
            }
        }
    }
}

// Split-K x ILP: 2048 blocks x 4 waves = 8192 waves (32/CU at VGPR<=64).
// Block = 2 query-pairs x 2 point-halves; wave pairs merge exactly via LDS.
__global__ __launch_bounds__(BLOCK, 8) void knn_kernel(const float* __restrict__ xyz,
                                                       float* __restrict__ out_idx,
                                                       float* __restrict__ out_pts)
{
    __shared__ float d_buf[2][2][2][KNN];            // [pair][query][half][rank]
    __shared__ int   i_buf[2][2][2][KNN];

    const int tid   = threadIdx.x;
    const int lane  = tid & 63;
    const int wv    = tid >> 6;
    const int pairw = wv >> 1;                       // pair within block (0/1)
    const int h     = wv & 1;                        // which point half
    const int qpg   = blockIdx.x * 2 + pairw;        // query-pair id [0, 4096)
    const int b     = qpg >> 10;                     // 1024 pairs per batch
    const int pr    = qpg & 1023;
    const size_t base = (size_t)b * NPTS * 3;

    const int qp0 = pr << 5;                         // stride-16 subsample
    const float qx0 = xyz[base + 3 * qp0 + 0];
    const float qy0 = xyz[base + 3 * qp0 + 1];
    const float qz0 = xyz[base + 3 * qp0 + 2];
    const float qx1 = xyz[base + 3 * qp0 + 48];
    const float qy1 = xyz[base + 3 * qp0 + 49];
    const float qz1 = xyz[base + 3 * qp0 + 50];

    const int g0 = b * NQ + (pr << 1);               // first global query id
    if (h == 0 && lane == 0) {
        out_pts[3 * g0 + 0] = qx0;
        out_pts[3 * g0 + 1] = qy0;
        out_pts[3 * g0 + 2] = qz0;
        out_pts[3 * g0 + 3] = qx1;
        out_pts[3 * g0 + 4] = qy1;
        out_pts[3 * g0 + 5] = qz1;
    }

    float ld = __builtin_inff();  int li = 0x7fffffff;
    float tau0 = __builtin_inff(), tau1 = __builtin_inff();
    float tg0  = __builtin_inff(), tg1  = __builtin_inff();

    // Lane's stream: 8 consecutive points (6 float4) per iter of its half.
    const float4* lp = (const float4*)(xyz + base) + h * (HALF * 3 / 4) + 6 * lane;
    const int pbase = h * HALF + PPL * lane;

    float4 A[6], Bf[6];
    load6(A, lp);                                    // prologue
    for (int k = 0; k < ITERS; k += 2) {             // double-buffered pipeline
        load6(Bf, lp + 384);                         // prefetch iter k+1
        step(A, pbase + (k << 9), lane,
             qx0, qy0, qz0, qx1, qy1, qz1, ld, li, tau0, tau1, tg0, tg1);
        if (k + 2 < ITERS)
            load6(A, lp + 768);                      // prefetch iter k+2
        step(Bf, pbase + ((k + 1) << 9), lane,
             qx0, qy0, qz0, qx1, qy1, qz1, ld, li, tau0, tau1, tg0, tg1);
        lp += 768;
    }

    // Publish this wave's two sorted 16-lists (exact distances + indices).
    if (lane < 32) {
        const int t = lane >> 4;
        d_buf[pairw][t][h][lane & 15] = ld;
        i_buf[pairw][t][h][lane & 15] = li;
    }
    __syncthreads();

    // Wave h==0 of each pair merges the two halves exactly: rank = count of
    // strictly-(d,idx)-less among the 32 candidates (disjoint point sets ->
    // total order; matches top_k's stable lowest-index-first tie-break).
    if (h == 0) {
        const int t = lane >> 5;                     // query within pair
        const int s = lane & 31;                     // candidate slot
        const float d = d_buf[pairw][t][s >> 4][s & 15];
        const int   i = i_buf[pairw][t][s >> 4][s & 15];
        int cnt = 0;
        #pragma unroll
        for (int r = 0; r < 32; ++r) {
            const float od = d_buf[pairw][t][r >> 4][r & 15];
            const int   oi = i_buf[pairw][t][r >> 4][r & 15];
            cnt += ((od < d) || (od == d && oi < i)) ? 1 : 0;
        }
        if (cnt < KNN)
            out_idx[(size_t)(g0 + t) * KNN + cnt] = (float)i;
    }
}

extern "C" void kernel_launch(void* const* d_in, const int* in_sizes, int n_in,
                              void* d_out, int out_size, void* d_ws, size_t ws_size,
                              hipStream_t stream) {
    const float* xyz = (const float*)d_in[0];
    float* out = (float*)d_out;
    float* out_idx = out;                                 // NB*NQ*KNN floats
    float* out_pts = out + (size_t)NB * NQ * KNN;         // NB*NQ*3 floats

    const int blocks = (NB * NQ / 2) / 2;                 // 2048 (2 pairs/block)
    knn_kernel<<<blocks, BLOCK, 0, stream>>>(xyz, out_idx, out_pts);
}

// Round 11
// 456.692 us; speedup vs baseline: 1.5446x; 1.5446x over previous
//
#include <hip/hip_runtime.h>
#include <stdint.h>

// Problem constants: B=4, N=32768, K=16, nqueries=2048, stride=16.
#define NPTS  32768
#define NQ    2048
#define KNN   16
#define NB    4
#define BLOCK 256
#define HALF  16384           // points per half-stream (split-K = 2)
#define PPL   8               // points per lane per iteration (16 ILP chains)
#define ITERS (HALF / (64 * PPL))   // 32

__device__ __forceinline__ int dpp_shr1_i(int x) {
    // row_shr:1 within 16-lane rows; row-start lane keeps old (bound_ctrl=0)
    return __builtin_amdgcn_update_dpp(x, x, 0x111, 0xf, 0xf, false);
}
__device__ __forceinline__ float dpp_shr1_f(float x) {
    return __int_as_float(dpp_shr1_i(__float_as_int(x)));
}
__device__ __forceinline__ float readlane_f(float x, int l) {
    return __int_as_float(__builtin_amdgcn_readlane(__float_as_int(x), l));
}

// Exact distributed top-16 for query T (0/1): sorted list (ascending by
// (dist,idx)) in lanes 16T..16T+15; lane 16T+15 holds the exact threshold tau.
// d is the EXACT numpy distance. tg = tau*(1+1e-5) (margin ~40x the
// fma-vs-numpy rounding gap) refreshed once per call (gate uses tg; the
// in-loop re-gate uses exact tau).
template <int T>
__device__ __forceinline__ void insert_all(float d, int p, int lane,
                                           float& ld, int& li, float& tau, float& tg)
{
    unsigned long long rem = __ballot(d <= tau);
    while (rem) {
        const int srcl = __ffsll(rem) - 1;           // wave-uniform
        const float wd = readlane_f(d, srcl);
        const int   wi = __builtin_amdgcn_readlane(p, srcl);
        const bool less = (ld < wd) || (ld == wd && li < wi);
        const unsigned long long lm = __ballot(less);
        const int pos = __popc((unsigned)((lm >> (16 * T)) & 0xffffull));
        const float pld = dpp_shr1_f(ld);
        const int   pli = dpp_shr1_i(li);
        if ((lane >> 4) == T) {
            const int gl = lane & 15;
            if (gl == pos)      { ld = wd;  li = wi;  }
            else if (gl > pos)  { ld = pld; li = pli; }
        }
        tau = readlane_f(ld, 16 * T + 15);
        rem &= rem - 1;
        if (rem) rem &= __ballot(d <= tau);          // re-gate survivors (exact)
    }
    tg = tau * 1.00001f;
}

__device__ __forceinline__ void load6(float4 dst[6], const float4* p) {
    #pragma unroll
    for (int t = 0; t < 6; ++t) dst[t] = p[t];
}

// One 512-point step: 8 pts/lane, 16 independent FMA-gate chains, exact
// recompute + exact insert for accepted slots.
__device__ __forceinline__ void step(const float4 c[6], int pb, int lane,
                                     float qx0, float qy0, float qz0,
                                     float qx1, float qy1, float qz1,
                                     float& ld, int& li,
                                     float& tau0, float& tau1,
                                     float& tg0, float& tg1)
{
    float px[PPL], py[PPL], pz[PPL];                 // pure register renames
    px[0] = c[0].x; py[0] = c[0].y; pz[0] = c[0].z;
    px[1] = c[0].w; py[1] = c[1].x; pz[1] = c[1].y;
    px[2] = c[1].z; py[2] = c[1].w; pz[2] = c[2].x;
    px[3] = c[2].y; py[3] = c[2].z; pz[3] = c[2].w;
    px[4] = c[3].x; py[4] = c[3].y; pz[4] = c[3].z;
    px[5] = c[3].w; py[5] = c[4].x; pz[5] = c[4].y;
    px[6] = c[4].z; py[6] = c[4].w; pz[6] = c[5].x;
    px[7] = c[5].y; py[7] = c[5].z; pz[7] = c[5].w;

    unsigned long long m0[PPL], m1[PPL], any = 0;
    #pragma unroll
    for (int j = 0; j < PPL; ++j) {                  // 16 independent chains
        const float ax = px[j] - qx0, ay = py[j] - qy0, az = pz[j] - qz0;
        const float g0 = __fmaf_rn(az, az, __fmaf_rn(ay, ay, __fmul_rn(ax, ax)));
        m0[j] = __ballot(g0 <= tg0);
        const float bx = px[j] - qx1, by = py[j] - qy1, bz = pz[j] - qz1;
        const float g1 = __fmaf_rn(bz, bz, __fmaf_rn(by, by, __fmul_rn(bx, bx)));
        m1[j] = __ballot(g1 <= tg1);
        any |= m0[j] | m1[j];
    }
    if (any) {
        #pragma unroll
        for (int j = 0; j < PPL; ++j) {
            if (m0[j]) {                             // exact numpy distance
                const float dx = __fadd_rn(px[j], -qx0);
                const float dy = __fadd_rn(py[j], -qy0);
                const float dz = __fadd_rn(pz[j], -qz0);
                const float d  = __fadd_rn(
                    __fadd_rn(__fmul_rn(dx, dx), __fmul_rn(dy, dy)),
                    __fmul_rn(dz, dz));
                insert_all<0>(d, pb + j, lane, ld, li, tau0, tg0);
            }
        }
        #pragma unroll
        for (int j = 0; j < PPL; ++j) {
            if (m1[j]) {
                const float dx = __fadd_rn(px[j], -qx1);
                const float dy = __fadd_rn(py[j], -qy1);
                const float dz = __fadd_rn(pz[j], -qz1);
                const float d  = __fadd_rn(
                    __fadd_rn(__fmul_rn(dx, dx), __fmul_rn(dy, dy)),
                    __fmul_rn(dz, dz));
                insert_all<1>(d, pb + j, lane, ld, li, tau1, tg1);
            }
        }
    }
}

// Split-K x ILP at 6 waves/SIMD: VGPR cap ~84 (no spill — R10's cap of 64
// spilled 3 GB to scratch), 24 waves/CU residency, full PPL=8 ILP engine.
// Block = 2 query-pairs x 2 point-halves; wave pairs merge exactly via LDS.
__global__ __launch_bounds__(BLOCK, 6) void knn_kernel(const float* __restrict__ xyz,
                                                       float* __restrict__ out_idx,
                                                       float* __restrict__ out_pts)
{
    __shared__ float d_buf[2][2][2][KNN];            // [pair][query][half][rank]
    __shared__ int   i_buf[2][2][2][KNN];

    const int tid   = threadIdx.x;
    const int lane  = tid & 63;
    const int wv    = tid >> 6;
    const int pairw = wv >> 1;                       // pair within block (0/1)
    const int h     = wv & 1;                        // which point half
    const int qpg   = blockIdx.x * 2 + pairw;        // query-pair id [0, 4096)
    const int b     = qpg >> 10;                     // 1024 pairs per batch
    const int pr    = qpg & 1023;
    const size_t base = (size_t)b * NPTS * 3;

    const int qp0 = pr << 5;                         // stride-16 subsample
    const float qx0 = xyz[base + 3 * qp0 + 0];
    const float qy0 = xyz[base + 3 * qp0 + 1];
    const float qz0 = xyz[base + 3 * qp0 + 2];
    const float qx1 = xyz[base + 3 * qp0 + 48];
    const float qy1 = xyz[base + 3 * qp0 + 49];
    const float qz1 = xyz[base + 3 * qp0 + 50];

    const int g0 = b * NQ + (pr << 1);               // first global query id
    if (h == 0 && lane == 0) {
        out_pts[3 * g0 + 0] = qx0;
        out_pts[3 * g0 + 1] = qy0;
        out_pts[3 * g0 + 2] = qz0;
        out_pts[3 * g0 + 3] = qx1;
        out_pts[3 * g0 + 4] = qy1;
        out_pts[3 * g0 + 5] = qz1;
    }

    float ld = __builtin_inff();  int li = 0x7fffffff;
    float tau0 = __builtin_inff(), tau1 = __builtin_inff();
    float tg0  = __builtin_inff(), tg1  = __builtin_inff();

    // Lane's stream: 8 consecutive points (6 float4) per iter of its half.
    const float4* lp = (const float4*)(xyz + base) + h * (HALF * 3 / 4) + 6 * lane;
    const int pbase = h * HALF + PPL * lane;

    float4 A[6], Bf[6];
    load6(A, lp);                                    // prologue
    for (int k = 0; k < ITERS; k += 2) {             // double-buffered pipeline
        load6(Bf, lp + 384);                         // prefetch iter k+1
        step(A, pbase + (k << 9), lane,
             qx0, qy0, qz0, qx1, qy1, qz1, ld, li, tau0, tau1, tg0, tg1);
        if (k + 2 < ITERS)
            load6(A, lp + 768);                      // prefetch iter k+2
        step(Bf, pbase + ((k + 1) << 9), lane,
             qx0, qy0, qz0, qx1, qy1, qz1, ld, li, tau0, tau1, tg0, tg1);
        lp += 768;
    }

    // Publish this wave's two sorted 16-lists (exact distances + indices).
    if (lane < 32) {
        const int t = lane >> 4;
        d_buf[pairw][t][h][lane & 15] = ld;
        i_buf[pairw][t][h][lane & 15] = li;
    }
    __syncthreads();

    // Wave h==0 of each pair merges the two halves exactly: rank = count of
    // strictly-(d,idx)-less among the 32 candidates (disjoint point sets ->
    // total order; matches top_k's stable lowest-index-first tie-break).
    if (h == 0) {
        const int t = lane >> 5;                     // query within pair
        const int s = lane & 31;                     // candidate slot
        const float d = d_buf[pairw][t][s >> 4][s & 15];
        const int   i = i_buf[pairw][t][s >> 4][s & 15];
        int cnt = 0;
        #pragma unroll
        for (int r = 0; r < 32; ++r) {
            const float od = d_buf[pairw][t][r >> 4][r & 15];
            const int   oi = i_buf[pairw][t][r >> 4][r & 15];
            cnt += ((od < d) || (od == d && oi < i)) ? 1 : 0;
        }
        if (cnt < KNN)
            out_idx[(size_t)(g0 + t) * KNN + cnt] = (float)i;
    }
}

extern "C" void kernel_launch(void* const* d_in, const int* in_sizes, int n_in,
                              void* d_out, int out_size, void* d_ws, size_t ws_size,
                              hipStream_t stream) {
    const float* xyz = (const float*)d_in[0];
    float* out = (float*)d_out;
    float* out_idx = out;                                 // NB*NQ*KNN floats
    float* out_pts = out + (size_t)NB * NQ * KNN;         // NB*NQ*3 floats

    const int blocks = (NB * NQ / 2) / 2;                 // 2048 (2 pairs/block)
    knn_kernel<<<blocks, BLOCK, 0, stream>>>(xyz, out_idx, out_pts);
}

// Round 12
// 255.565 us; speedup vs baseline: 2.7602x; 1.7870x over previous
//
#include <hip/hip_runtime.h>
#include <stdint.h>

// Problem constants: B=4, N=32768, K=16, nqueries=2048, stride=16.
#define NPTS  32768
#define NQ    2048
#define KNN   16
#define NB    4
#define BLOCK 256
#define HALF  16384           // points per half-stream (split-K = 2)
#define MARGIN 2e-4f          // >= 2x worst-case |(g+qn) - d_numpy| for |p|^2<=49

__device__ __forceinline__ int dpp_shr1_i(int x) {
    // row_shr:1 within 16-lane rows; row-start lane keeps old (bound_ctrl=0)
    return __builtin_amdgcn_update_dpp(x, x, 0x111, 0xf, 0xf, false);
}
__device__ __forceinline__ float dpp_shr1_f(float x) {
    return __int_as_float(dpp_shr1_i(__float_as_int(x)));
}
__device__ __forceinline__ float readlane_f(float x, int l) {
    return __int_as_float(__builtin_amdgcn_readlane(__float_as_int(x), l));
}

// Exact distributed top-16 for query T (0..3): sorted list (ascending by
// (dist,idx)) in lanes 16T..16T+15; lane 16T+15 holds the exact threshold tau.
// d is the EXACT numpy distance. tga = (tau - qn) + MARGIN is the conservative
// norm-trick gate threshold, refreshed when tau changes.
template <int T>
__device__ __forceinline__ void insert_all(float d, int p, int lane,
                                           float& ld, int& li, float& tau,
                                           float& tga, float qn)
{
    unsigned long long rem = __ballot(d <= tau);
    while (rem) {
        const int srcl = __ffsll(rem) - 1;           // wave-uniform
        const float wd = readlane_f(d, srcl);
        const int   wi = __builtin_amdgcn_readlane(p, srcl);
        const bool less = (ld < wd) || (ld == wd && li < wi);
        const unsigned long long lm = __ballot(less);
        const int pos = __popc((unsigned)((lm >> (16 * T)) & 0xffffull));
        const float pld = dpp_shr1_f(ld);
        const int   pli = dpp_shr1_i(li);
        if ((lane >> 4) == T) {
            const int gl = lane & 15;
            if (gl == pos)      { ld = wd;  li = wi;  }
            else if (gl > pos)  { ld = pld; li = pli; }
        }
        tau = readlane_f(ld, 16 * T + 15);
        rem &= rem - 1;
        if (rem) rem &= __ballot(d <= tau);          // re-gate survivors (exact)
    }
    tga = (tau - qn) + MARGIN;
}

// Pack (x, y, z, |p|^2) per point into workspace.
__global__ __launch_bounds__(256) void prep_kernel(const float* __restrict__ xyz,
                                                   float4* __restrict__ pts4)
{
    const int i = blockIdx.x * 256 + threadIdx.x;    // [0, NB*NPTS)
    const float x = xyz[3 * i + 0];
    const float y = xyz[3 * i + 1];
    const float z = xyz[3 * i + 2];
    pts4[i] = make_float4(x, y, z,
                          __fmaf_rn(z, z, __fmaf_rn(y, y, __fmul_rn(x, x))));
}

// 1024 blocks x 4 waves = 4096 waves. Wave = (query-quad, half). Gate:
// g = fma(pz,-2qz, fma(py,-2qy, fma(px,-2qx, pn))) <= (tau - qn) + MARGIN.
// 4 queries/wave <-> the four 16-lane DPP rows. Halves merged exactly via LDS.
__global__ __launch_bounds__(BLOCK, 4) void knn_kernel(const float4* __restrict__ pts4,
                                                       const float* __restrict__ xyz,
                                                       float* __restrict__ out_idx,
                                                       float* __restrict__ out_pts)
{
    __shared__ float d_buf[2][4][2][KNN];            // [quad][query][half][rank]
    __shared__ int   i_buf[2][4][2][KNN];

    const int tid   = threadIdx.x;
    const int lane  = tid & 63;
    const int wv    = tid >> 6;
    const int pairw = wv >> 1;                       // quad within block (0/1)
    const int h     = wv & 1;                        // point half
    const int qq    = blockIdx.x * 2 + pairw;        // quad id [0, 2048)
    const int b     = qq >> 9;                       // 512 quads per batch
    const int qr    = qq & 511;
    const size_t base4 = (size_t)b * NPTS;

    // 4 query points (stride-16 subsample): q_t at point index 64*qr + 16*t
    float m2qx[4], m2qy[4], m2qz[4], qn[4], tau[4], tga[4];
    #pragma unroll
    for (int t = 0; t < 4; ++t) {
        const float4 q4 = pts4[base4 + 64 * qr + 16 * t];
        m2qx[t] = -2.f * q4.x;                       // exact (x2 exact in fp)
        m2qy[t] = -2.f * q4.y;
        m2qz[t] = -2.f * q4.z;
        qn[t]   = q4.w;
        tau[t]  = __builtin_inff();
        tga[t]  = __builtin_inff();
    }

    const int g0 = b * NQ + 4 * qr;                  // first global query id
    if (h == 0 && lane < 12) {                       // 12 floats of out_pts
        const int t = (lane * 11) >> 5;              // lane/3 for lane<12
        const int c = lane - 3 * t;
        out_pts[3 * g0 + lane] =
            xyz[(size_t)b * NPTS * 3 + 3 * (64 * qr + 16 * t) + c];
    }

    float ld = __builtin_inff();  int li = 0x7fffffff;

    // Lane's stream: points {lane, lane+64, lane+128, lane+192} per 256-chunk
    // (consecutive-lane float4 loads: 1 KB contiguous per instruction).
    const float4* lp = pts4 + base4 + h * HALF + lane;

    #pragma unroll 2
    for (int k = 0; k < HALF / 256; ++k) {           // 64 chunks
        const float4 P0 = lp[256 * k + 0];
        const float4 P1 = lp[256 * k + 64];
        const float4 P2 = lp[256 * k + 128];
        const float4 P3 = lp[256 * k + 192];

        unsigned long long ms[16];
        #pragma unroll
        for (int t = 0; t < 4; ++t) {                // 16 independent chains
            float g;
            g = __fmaf_rn(P0.z, m2qz[t], __fmaf_rn(P0.y, m2qy[t],
                 __fmaf_rn(P0.x, m2qx[t], P0.w)));
            ms[4 * t + 0] = __ballot(g <= tga[t]);
            g = __fmaf_rn(P1.z, m2qz[t], __fmaf_rn(P1.y, m2qy[t],
                 __fmaf_rn(P1.x, m2qx[t], P1.w)));
            ms[4 * t + 1] = __ballot(g <= tga[t]);
            g = __fmaf_rn(P2.z, m2qz[t], __fmaf_rn(P2.y, m2qy[t],
                 __fmaf_rn(P2.x, m2qx[t], P2.w)));
            ms[4 * t + 2] = __ballot(g <= tga[t]);
            g = __fmaf_rn(P3.z, m2qz[t], __fmaf_rn(P3.y, m2qy[t],
                 __fmaf_rn(P3.x, m2qx[t], P3.w)));
            ms[4 * t + 3] = __ballot(g <= tga[t]);
        }

        unsigned long long any = 0;
        #pragma unroll
        for (int s = 0; s < 16; ++s) any |= ms[s];

        if (any) {
            const int pbk = h * HALF + 256 * k + lane;
            // Slow path (rare): exact numpy distance; q recovered exactly as
            // -0.5 * m2q. ms[] is wave-uniform -> uniform branch, all lanes
            // enter so the list lanes participate; rem re-filters exactly.
            #define SLOW(T, J, PV)                                             \
                if (ms[4 * T + J]) {                                           \
                    const float qxv = m2qx[T] * -0.5f;                         \
                    const float qyv = m2qy[T] * -0.5f;                         \
                    const float qzv = m2qz[T] * -0.5f;                         \
                    const float dx = __fadd_rn(PV.x, -qxv);                    \
                    const float dy = __fadd_rn(PV.y, -qyv);                    \
                    const float dz = __fadd_rn(PV.z, -qzv);                    \
                    const float d  = __fadd_rn(                                \
                        __fadd_rn(__fmul_rn(dx, dx), __fmul_rn(dy, dy)),       \
                        __fmul_rn(dz, dz));                                    \
                    insert_all<T>(d, pbk + 64 * J, lane, ld, li,               \
                                  tau[T], tga[T], qn[T]);                      \
                }
            SLOW(0, 0, P0) SLOW(0, 1, P1) SLOW(0, 2, P2) SLOW(0, 3, P3)
            SLOW(1, 0, P0) SLOW(1, 1, P1) SLOW(1, 2, P2) SLOW(1, 3, P3)
            SLOW(2, 0, P0) SLOW(2, 1, P1) SLOW(2, 2, P2) SLOW(2, 3, P3)
            SLOW(3, 0, P0) SLOW(3, 1, P1) SLOW(3, 2, P2) SLOW(3, 3, P3)
            #undef SLOW
        }
    }

    // Publish the 4 sorted 16-lists (group T in lanes 16T..16T+15).
    {
        const int t = lane >> 4, r = lane & 15;
        d_buf[pairw][t][h][r] = ld;
        i_buf[pairw][t][h][r] = li;
    }
    __syncthreads();

    // Exact merge: 256 threads = 2 quads x 4 queries x 32 candidates. Rank =
    // count of strictly-(d,idx)-less among the 32 (disjoint halves -> total
    // order; matches top_k's stable lowest-index-first tie-break).
    {
        const int pairm = tid >> 7;
        const int rest  = tid & 127;
        const int tq    = rest >> 5;
        const int s     = rest & 31;
        const float d = d_buf[pairm][tq][s >> 4][s & 15];
        const int   i = i_buf[pairm][tq][s >> 4][s & 15];
        int cnt = 0;
        #pragma unroll
        for (int r = 0; r < 32; ++r) {
            const float od = d_buf[pairm][tq][r >> 4][r & 15];
            const int   oi = i_buf[pairm][tq][r >> 4][r & 15];
            cnt += ((od < d) || (od == d && oi < i)) ? 1 : 0;
        }
        if (cnt < KNN) {
            const int qq2 = blockIdx.x * 2 + pairm;
            const int b2 = qq2 >> 9, qr2 = qq2 & 511;
            out_idx[(size_t)(b2 * NQ + 4 * qr2 + tq) * KNN + cnt] = (float)i;
        }
    }
}

extern "C" void kernel_launch(void* const* d_in, const int* in_sizes, int n_in,
                              void* d_out, int out_size, void* d_ws, size_t ws_size,
                              hipStream_t stream) {
    const float* xyz = (const float*)d_in[0];
    float* out = (float*)d_out;
    float* out_idx = out;                                 // NB*NQ*KNN floats
    float* out_pts = out + (size_t)NB * NQ * KNN;         // NB*NQ*3 floats
    float4* pts4 = (float4*)d_ws;                         // 2 MB scratch

    prep_kernel<<<(NB * NPTS) / 256, 256, 0, stream>>>(xyz, pts4);
    knn_kernel<<<1024, BLOCK, 0, stream>>>(pts4, xyz, out_idx, out_pts);
}